// Round 1
// baseline (835.933 us; speedup 1.0000x reference)
//
#include <hip/hip_runtime.h>
#include <cstdint>
#include <cstddef>

// ScaledDotProduct: qp=q@Wq^T+bq; kp=k@Wk^T+bk; vp=v@Wv^T+bv;
// z=sigmoid(qp@kp^T/16); out=z@vp.  All GEMMs bf16 MFMA (fp32 accum).

typedef __bf16 bf16;
typedef __bf16 v8bf __attribute__((ext_vector_type(8)));
typedef __bf16 v4bf __attribute__((ext_vector_type(4)));
typedef float  v4f  __attribute__((ext_vector_type(4)));

#define DIMV  1024
#define QKD   256
#define BATCH 4
#define SEQ   4096

#define TM 128
#define TN 128
#define BK 32

// ---------------- fp32 -> bf16 cast, 4 elems/thread ----------------
__global__ __launch_bounds__(256) void cast_f32_bf16(const float* __restrict__ in,
                                                     bf16* __restrict__ out, int n4) {
  int i = blockIdx.x * 256 + threadIdx.x;
  if (i >= n4) return;
  const float4 v = reinterpret_cast<const float4*>(in)[i];
  v4bf o;
  o[0] = (bf16)v.x; o[1] = (bf16)v.y; o[2] = (bf16)v.z; o[3] = (bf16)v.w;
  reinterpret_cast<v4bf*>(out)[i] = o;
}

__device__ __forceinline__ void gload_lds16(const void* g, void* l) {
  __builtin_amdgcn_global_load_lds((const __attribute__((address_space(1))) void*)g,
                                   (__attribute__((address_space(3))) void*)l,
                                   16, 0, 0);
}

// NT GEMM: C[m,n] = sum_k A[m,k]*B[n,k]  (A: MxK row-major, B: NxK row-major)
// MODE 0: bf16 out = acc + bias[n], row-major (ldc)
// MODE 1: bf16 out = acc + bias[n], TRANSPOSED store C[n*ldc + m]
// MODE 2: bf16 out = sigmoid(acc/16), row-major
// MODE 3: f32  out = acc, row-major
template <int MODE>
__global__ __launch_bounds__(256) void gemm_nt(const bf16* __restrict__ A,
                                               const bf16* __restrict__ B,
                                               const float* __restrict__ bias,
                                               void* __restrict__ Cv,
                                               int M, int N, int K, int ldc) {
  __shared__ __align__(16) bf16 As[TM * BK];  // 8 KB
  __shared__ __align__(16) bf16 Bs[TN * BK];  // 8 KB
  const int tid  = threadIdx.x;
  const int wave = tid >> 6;
  const int lane = tid & 63;
  const int row0 = blockIdx.x * TM;
  const int col0 = blockIdx.y * TN;
  const int wm = (wave & 1) * 64;   // 2x2 waves, each owns 64x64
  const int wn = (wave >> 1) * 64;
  const int lm   = lane & 15;
  const int quad = lane >> 4;

  v4f acc[4][4] = {};

  const char* gA = (const char*)A;
  const char* gB = (const char*)B;
  const size_t strideA = (size_t)K * 2;

  // staging: tile is 128 rows x 64 bytes; thread covers 16B at byteidx =
  // issue*4096 + tid*16; row = byteidx/64, kbyte = byteidx%64.
  const int r0s = (tid * 16) >> 6, kb0 = (tid * 16) & 63;
  const int r1s = r0s + 64,        kb1 = kb0;
  char* ldsA = (char*)As + wave * 1024;  // wave-uniform base; HW adds lane*16
  char* ldsB = (char*)Bs + wave * 1024;

  const int kIters = K / BK;
  for (int kt = 0; kt < kIters; ++kt) {
    const size_t kOff = (size_t)kt * (BK * 2);
    gload_lds16(gA + (size_t)(row0 + r0s) * strideA + kOff + kb0, ldsA);
    gload_lds16(gA + (size_t)(row0 + r1s) * strideA + kOff + kb1, ldsA + 4096);
    gload_lds16(gB + (size_t)(col0 + r0s) * strideA + kOff + kb0, ldsB);
    gload_lds16(gB + (size_t)(col0 + r1s) * strideA + kOff + kb1, ldsB + 4096);
    __syncthreads();  // drains vmcnt for global_load_lds + barrier

    v8bf av[4], bv[4];
#pragma unroll
    for (int i = 0; i < 4; ++i)
      av[i] = *(const v8bf*)&As[(wm + i * 16 + lm) * BK + quad * 8];
#pragma unroll
    for (int j = 0; j < 4; ++j)
      bv[j] = *(const v8bf*)&Bs[(wn + j * 16 + lm) * BK + quad * 8];
#pragma unroll
    for (int i = 0; i < 4; ++i)
#pragma unroll
      for (int j = 0; j < 4; ++j)
        acc[i][j] = __builtin_amdgcn_mfma_f32_16x16x32_bf16(av[i], bv[j], acc[i][j], 0, 0, 0);
    __syncthreads();
  }

  // epilogue: C/D layout col=lane&15, row=quad*4+reg  [m89-verified]
#pragma unroll
  for (int i = 0; i < 4; ++i) {
    const int grow0 = row0 + wm + i * 16 + quad * 4;
#pragma unroll
    for (int j = 0; j < 4; ++j) {
      const int gcol = col0 + wn + j * 16 + lm;
      float badd = 0.f;
      if (MODE == 0 || MODE == 1) badd = bias[gcol];
#pragma unroll
      for (int r = 0; r < 4; ++r) {
        const int grow = grow0 + r;
        float v = acc[i][j][r];
        if (MODE == 0 || MODE == 1) v += badd;
        if (MODE == 2) v = 1.f / (1.f + __expf(v * -0.0625f));  // sigmoid(v/16)
        if (MODE == 3) {
          ((float*)Cv)[(size_t)grow * ldc + gcol] = v;
        } else if (MODE == 1) {
          ((bf16*)Cv)[(size_t)gcol * ldc + grow] = (bf16)v;
        } else {
          ((bf16*)Cv)[(size_t)grow * ldc + gcol] = (bf16)v;
        }
      }
    }
  }
}

extern "C" void kernel_launch(void* const* d_in, const int* in_sizes, int n_in,
                              void* d_out, int out_size, void* d_ws, size_t ws_size,
                              hipStream_t stream) {
  const float* q  = (const float*)d_in[0];
  const float* k  = (const float*)d_in[1];
  const float* v  = (const float*)d_in[2];
  const float* Wq = (const float*)d_in[3];
  const float* bq = (const float*)d_in[4];
  const float* Wk = (const float*)d_in[5];
  const float* bk = (const float*)d_in[6];
  const float* Wv = (const float*)d_in[7];
  const float* bv = (const float*)d_in[8];
  float* out = (float*)d_out;

  // ws layout (bytes); scratch is time-shared: q16 -> k16 -> v16 -> z (per batch)
  char* ws = (char*)d_ws;
  bf16* scratch = (bf16*)(ws);              // 33554432 B
  bf16* Wq16    = (bf16*)(ws + 33554432);   //   524288 B
  bf16* Wk16    = (bf16*)(ws + 34078720);   //   524288 B
  bf16* Wv16    = (bf16*)(ws + 34603008);   //  2097152 B
  bf16* qp16    = (bf16*)(ws + 36700160);   //  8388608 B
  bf16* kp16    = (bf16*)(ws + 45088768);   //  8388608 B
  bf16* vpT     = (bf16*)(ws + 53477376);   // 33554432 B  -> total 87031808 B

  const int NQKV = BATCH * SEQ * DIMV;  // 16777216

  auto cast = [&](const float* src, bf16* dst, int n) {
    int n4 = n / 4;
    cast_f32_bf16<<<dim3((n4 + 255) / 256), dim3(256), 0, stream>>>(src, dst, n4);
  };

  cast(Wq, Wq16, QKD * DIMV);
  cast(Wk, Wk16, QKD * DIMV);
  cast(Wv, Wv16, DIMV * DIMV);

  // qp = q @ Wq^T + bq  -> bf16 [B*S, 256]
  cast(q, scratch, NQKV);
  gemm_nt<0><<<dim3(BATCH * SEQ / TM, QKD / TN), dim3(256), 0, stream>>>(
      scratch, Wq16, bq, qp16, BATCH * SEQ, QKD, DIMV, QKD);

  // kp = k @ Wk^T + bk  -> bf16 [B*S, 256]
  cast(k, scratch, NQKV);
  gemm_nt<0><<<dim3(BATCH * SEQ / TM, QKD / TN), dim3(256), 0, stream>>>(
      scratch, Wk16, bk, kp16, BATCH * SEQ, QKD, DIMV, QKD);

  // vpT[b][n][s] = (v @ Wv^T + bv) transposed  -> bf16 [B][1024][4096]
  cast(v, scratch, NQKV);
  for (int b = 0; b < BATCH; ++b) {
    gemm_nt<1><<<dim3(SEQ / TM, DIMV / TN), dim3(256), 0, stream>>>(
        scratch + (size_t)b * SEQ * DIMV, Wv16, bv,
        vpT + (size_t)b * DIMV * SEQ, SEQ, DIMV, DIMV, SEQ);
  }

  // per batch: z = sigmoid(qp@kp^T/16) into scratch; out = z @ vp
  for (int b = 0; b < BATCH; ++b) {
    gemm_nt<2><<<dim3(SEQ / TM, SEQ / TN), dim3(256), 0, stream>>>(
        qp16 + (size_t)b * SEQ * QKD, kp16 + (size_t)b * SEQ * QKD, nullptr,
        scratch, SEQ, SEQ, QKD, SEQ);
    gemm_nt<3><<<dim3(SEQ / TM, DIMV / TN), dim3(256), 0, stream>>>(
        scratch, vpT + (size_t)b * DIMV * SEQ, nullptr,
        out + (size_t)b * SEQ * DIMV, SEQ, DIMV, SEQ, DIMV);
  }
}

// Round 2
// 772.429 us; speedup vs baseline: 1.0822x; 1.0822x over previous
//
#include <hip/hip_runtime.h>
#include <cstdint>
#include <cstddef>

// ScaledDotProduct: qp=q@Wq^T+bq; kp=k@Wk^T+bk; vp=v@Wv^T+bv;
// z=sigmoid(qp@kp^T/16); out=z@vp.  All GEMMs bf16 MFMA (fp32 accum).
// R2: grid/occupancy fixes (split-K out, batched vp, dual qp/kp) +
//     XOR-swizzled LDS staging to kill 8-way bank conflicts.

typedef __bf16 bf16;
typedef __bf16 v8bf __attribute__((ext_vector_type(8)));
typedef __bf16 v4bf __attribute__((ext_vector_type(4)));
typedef float  v4f  __attribute__((ext_vector_type(4)));

#define DIMV  1024
#define QKD   256
#define BATCH 4
#define SEQ   4096

#define TM 128
#define TN 128
#define BK 32

// ---------------- fp32 -> bf16 cast, 4 elems/thread ----------------
__global__ __launch_bounds__(256) void cast_f32_bf16(const float* __restrict__ in,
                                                     bf16* __restrict__ out, int n4) {
  int i = blockIdx.x * 256 + threadIdx.x;
  if (i >= n4) return;
  const float4 v = reinterpret_cast<const float4*>(in)[i];
  v4bf o;
  o[0] = (bf16)v.x; o[1] = (bf16)v.y; o[2] = (bf16)v.z; o[3] = (bf16)v.w;
  reinterpret_cast<v4bf*>(out)[i] = o;
}

__global__ __launch_bounds__(256) void zero_f32(float4* __restrict__ p, int n4) {
  int i = blockIdx.x * 256 + threadIdx.x;
  if (i < n4) p[i] = float4{0.f, 0.f, 0.f, 0.f};
}

__device__ __forceinline__ void gload_lds16(const void* g, void* l) {
  __builtin_amdgcn_global_load_lds((const __attribute__((address_space(1))) void*)g,
                                   (__attribute__((address_space(3))) void*)l,
                                   16, 0, 0);
}

// NT GEMM: C[m,n] = sum_k A[m,k]*B[n,k]  (A: MxK rows lda, B: NxK rows ldb)
// blockIdx.z offsets A/B/C by As_z/Bs_z/Cs_z elements (dual-launch / split-K).
// MODE 0: bf16 out = acc + bias[n], row-major (ldc); bias = z?bias1:bias0
// MODE 1: bf16 out = acc + bias0[n], batch-transposed store:
//         b=grow>>12, s=grow&4095 -> C[((b*DIMV+gcol)*SEQ + s)]
// MODE 2: bf16 out = sigmoid(acc/16), row-major
// MODE 4: f32 unsafeAtomicAdd into C row-major (split-K)
template <int MODE>
__global__ __launch_bounds__(256) void gemm_nt(
    const bf16* __restrict__ A, long As_z,
    const bf16* __restrict__ B, long Bs_z,
    const float* __restrict__ bias0, const float* __restrict__ bias1,
    void* __restrict__ Cv, long Cs_z,
    int K, int lda, int ldb, int ldc) {
  __shared__ __align__(16) bf16 As[TM * BK];  // 8 KB
  __shared__ __align__(16) bf16 Bs[TN * BK];  // 8 KB
  const int tid  = threadIdx.x;
  const int wave = tid >> 6;
  const int lane = tid & 63;
  const int zb   = blockIdx.z;
  A = A + (size_t)zb * As_z;
  B = B + (size_t)zb * Bs_z;
  const float* bias = (MODE == 0 && zb) ? bias1 : bias0;

  const int row0 = blockIdx.x * TM;
  const int col0 = blockIdx.y * TN;
  const int wm = (wave & 1) * 64;   // 2x2 waves, each owns 64x64
  const int wn = (wave >> 1) * 64;
  const int lm   = lane & 15;
  const int quad = lane >> 4;

  v4f acc[4][4] = {};

  const char* gA = (const char*)A;
  const char* gB = (const char*)B;
  const size_t sA = (size_t)lda * 2;
  const size_t sB = (size_t)ldb * 2;

  // XOR-swizzled staging: LDS granule (row*4 + qs) holds global 16B chunk
  // (row, q = qs ^ ((row>>1)&3)).  Lane layout of global_load_lds is fixed
  // (base + lane*16), so we permute the GLOBAL address instead.
  const int row_s = tid >> 2;                      // 0..63 (issue 0)
  const int qg    = (tid & 3) ^ ((row_s >> 1) & 3);  // same for issue 1 (+64 rows)
  const int kb    = qg * 16;
  char* ldsA = (char*)As + wave * 1024;  // wave-uniform base; HW adds lane*16
  char* ldsB = (char*)Bs + wave * 1024;

  const int kIters = K / BK;
  for (int kt = 0; kt < kIters; ++kt) {
    const size_t kOff = (size_t)kt * (BK * 2);
    gload_lds16(gA + (size_t)(row0 + row_s) * sA + kOff + kb, ldsA);
    gload_lds16(gA + (size_t)(row0 + row_s + 64) * sA + kOff + kb, ldsA + 4096);
    gload_lds16(gB + (size_t)(col0 + row_s) * sB + kOff + kb, ldsB);
    gload_lds16(gB + (size_t)(col0 + row_s + 64) * sB + kOff + kb, ldsB + 4096);
    __syncthreads();  // drains vmcnt for global_load_lds + barrier

    // read-side swizzle: (row>>1)&3 == (lane>>1)&3 for our row decomposition
    const int sw8 = ((quad ^ ((lane >> 1) & 3)) * 8);
    v8bf av[4], bv[4];
#pragma unroll
    for (int i = 0; i < 4; ++i)
      av[i] = *(const v8bf*)&As[(wm + i * 16 + lm) * BK + sw8];
#pragma unroll
    for (int j = 0; j < 4; ++j)
      bv[j] = *(const v8bf*)&Bs[(wn + j * 16 + lm) * BK + sw8];
#pragma unroll
    for (int i = 0; i < 4; ++i)
#pragma unroll
      for (int j = 0; j < 4; ++j)
        acc[i][j] = __builtin_amdgcn_mfma_f32_16x16x32_bf16(av[i], bv[j], acc[i][j], 0, 0, 0);
    __syncthreads();
  }

  // epilogue: C/D layout col=lane&15, row=quad*4+reg  [m89-verified]
#pragma unroll
  for (int i = 0; i < 4; ++i) {
    const int grow0 = row0 + wm + i * 16 + quad * 4;
#pragma unroll
    for (int j = 0; j < 4; ++j) {
      const int gcol = col0 + wn + j * 16 + lm;
      float badd = 0.f;
      if (MODE == 0 || MODE == 1) badd = bias[gcol];
      if (MODE == 1) {
        // batch-transposed vpT store, 4 consecutive s -> one 8B store
        const int b = grow0 >> 12, s = grow0 & 4095;
        v4bf o;
#pragma unroll
        for (int r = 0; r < 4; ++r) o[r] = (bf16)(acc[i][j][r] + badd);
        *(v4bf*)&((bf16*)Cv)[((size_t)(b * DIMV + gcol)) * SEQ + s] = o;
      } else {
#pragma unroll
        for (int r = 0; r < 4; ++r) {
          const int grow = grow0 + r;
          float v = acc[i][j][r];
          if (MODE == 0) {
            ((bf16*)Cv)[(size_t)zb * Cs_z + (size_t)grow * ldc + gcol] = (bf16)(v + badd);
          } else if (MODE == 2) {
            v = 1.f / (1.f + __expf(v * -0.0625f));  // sigmoid(v/16)
            ((bf16*)Cv)[(size_t)grow * ldc + gcol] = (bf16)v;
          } else {  // MODE 4
            unsafeAtomicAdd(&((float*)Cv)[(size_t)grow * ldc + gcol], v);
          }
        }
      }
    }
  }
}

extern "C" void kernel_launch(void* const* d_in, const int* in_sizes, int n_in,
                              void* d_out, int out_size, void* d_ws, size_t ws_size,
                              hipStream_t stream) {
  const float* q  = (const float*)d_in[0];
  const float* k  = (const float*)d_in[1];
  const float* v  = (const float*)d_in[2];
  const float* Wq = (const float*)d_in[3];
  const float* bq = (const float*)d_in[4];
  const float* Wk = (const float*)d_in[5];
  const float* bk = (const float*)d_in[6];
  const float* Wv = (const float*)d_in[7];
  const float* bv = (const float*)d_in[8];
  float* out = (float*)d_out;

  // ws layout (bytes), total 87 MB (proven safe in R1):
  // scratch time-shared: q16 -> v16 -> z (per batch); vpT region time-shared:
  // k16 (until kp GEMM done) -> vpT.
  char* ws = (char*)d_ws;
  bf16* scratch = (bf16*)(ws);              // 33554432 B
  bf16* Wq16    = (bf16*)(ws + 33554432);   //   524288 B
  bf16* Wk16    = (bf16*)(ws + 34078720);   //   524288 B
  bf16* Wv16    = (bf16*)(ws + 34603008);   //  2097152 B
  bf16* qp16    = (bf16*)(ws + 36700160);   //  8388608 B
  bf16* kp16    = (bf16*)(ws + 45088768);   //  8388608 B
  bf16* vpT     = (bf16*)(ws + 53477376);   // 33554432 B  -> total 87031808 B
  bf16* k16     = vpT;                      // time-shared

  const int NQKV = BATCH * SEQ * DIMV;  // 16777216

  auto cast = [&](const float* src, bf16* dst, int n) {
    int n4 = n / 4;
    cast_f32_bf16<<<dim3((n4 + 255) / 256), dim3(256), 0, stream>>>(src, dst, n4);
  };

  cast(Wq, Wq16, QKD * DIMV);
  cast(Wk, Wk16, QKD * DIMV);
  cast(Wv, Wv16, DIMV * DIMV);
  cast(q, scratch, NQKV);  // q16
  cast(k, k16, NQKV);      // k16 (in vpT region)

  // qp/kp dual launch: z=0 -> qp = q16@Wq16^T+bq; z=1 -> kp = k16@Wk16^T+bk
  gemm_nt<0><<<dim3(BATCH * SEQ / TM, QKD / TN, 2), dim3(256), 0, stream>>>(
      scratch, (long)(k16 - scratch), Wq16, (long)(QKD * DIMV), bq, bk,
      qp16, (long)(kp16 - qp16), DIMV, DIMV, DIMV, QKD);

  // vpT: all batches in one launch (flat M=16384), batch-decomposed T-store
  cast(v, scratch, NQKV);  // v16 (q16 dead)
  gemm_nt<1><<<dim3(BATCH * SEQ / TM, DIMV / TN, 1), dim3(256), 0, stream>>>(
      scratch, 0L, Wv16, 0L, bv, nullptr,
      vpT, 0L, DIMV, DIMV, DIMV, 0);   // overwrites k16 (kp done)

  // zero d_out once (split-K accumulates with atomics)
  {
    int n4 = BATCH * SEQ * DIMV / 4;
    zero_f32<<<dim3((n4 + 255) / 256), dim3(256), 0, stream>>>((float4*)out, n4);
  }

  // per batch: z = sigmoid(qp@kp^T/16) into scratch; out += z @ vp (split-K=4)
  for (int b = 0; b < BATCH; ++b) {
    gemm_nt<2><<<dim3(SEQ / TM, SEQ / TN, 1), dim3(256), 0, stream>>>(
        qp16 + (size_t)b * SEQ * QKD, 0L, kp16 + (size_t)b * SEQ * QKD, 0L,
        nullptr, nullptr, scratch, 0L, QKD, QKD, QKD, SEQ);
    gemm_nt<4><<<dim3(SEQ / TM, DIMV / TN, 4), dim3(256), 0, stream>>>(
        scratch, 1024L, vpT + (size_t)b * DIMV * SEQ, 1024L,
        nullptr, nullptr, out + (size_t)b * SEQ * DIMV, 0L,
        SEQ / 4, SEQ, SEQ, DIMV);
  }
}

// Round 3
// 597.407 us; speedup vs baseline: 1.3993x; 1.2930x over previous
//
#include <hip/hip_runtime.h>
#include <cstdint>
#include <cstddef>

// ScaledDotProduct: qp=q@Wq^T+bq; kp=k@Wk^T+bk; vp=v@Wv^T+bv;
// z=sigmoid(qp@kp^T/16); out=z@vp.  All GEMMs bf16 MFMA (fp32 accum).
// R3: batch all 4 batches into single dispatches via blockIdx.z (full K=4096
//     K-loop, no split-K atomics). z for the whole group materialized at once;
//     ws_size-dependent grouping (4/2/1 batches) chosen deterministically.

typedef __bf16 bf16;
typedef __bf16 v8bf __attribute__((ext_vector_type(8)));
typedef __bf16 v4bf __attribute__((ext_vector_type(4)));
typedef float  v4f  __attribute__((ext_vector_type(4)));

#define DIMV  1024
#define QKD   256
#define BATCH 4
#define SEQ   4096

#define TM 128
#define TN 128
#define BK 32

// ---------------- fp32 -> bf16 cast, 4 elems/thread ----------------
__global__ __launch_bounds__(256) void cast_f32_bf16(const float* __restrict__ in,
                                                     bf16* __restrict__ out, int n4) {
  int i = blockIdx.x * 256 + threadIdx.x;
  if (i >= n4) return;
  const float4 v = reinterpret_cast<const float4*>(in)[i];
  v4bf o;
  o[0] = (bf16)v.x; o[1] = (bf16)v.y; o[2] = (bf16)v.z; o[3] = (bf16)v.w;
  reinterpret_cast<v4bf*>(out)[i] = o;
}

__device__ __forceinline__ void gload_lds16(const void* g, void* l) {
  __builtin_amdgcn_global_load_lds((const __attribute__((address_space(1))) void*)g,
                                   (__attribute__((address_space(3))) void*)l,
                                   16, 0, 0);
}

// NT GEMM: C[m,n] = sum_k A[m,k]*B[n,k]  (A: MxK rows lda, B: NxK rows ldb)
// blockIdx.z offsets A/B/C by As_z/Bs_z/Cs_z ELEMENTS (batch / dual-launch).
// MODE 0: bf16 out = acc + bias[n], row-major (ldc); bias = zb?bias1:bias0
// MODE 1: bf16 out = acc + bias0[n], batch-transposed store:
//         b=grow>>12, s=grow&4095 -> C[((b*DIMV+gcol)*SEQ + s)]
// MODE 2: bf16 out = sigmoid(acc/16), row-major
// MODE 3: f32 out = acc, row-major
template <int MODE>
__global__ __launch_bounds__(256) void gemm_nt(
    const bf16* __restrict__ A, long As_z,
    const bf16* __restrict__ B, long Bs_z,
    const float* __restrict__ bias0, const float* __restrict__ bias1,
    void* __restrict__ Cv, long Cs_z,
    int K, int lda, int ldb, int ldc) {
  __shared__ __align__(16) bf16 As[TM * BK];  // 8 KB
  __shared__ __align__(16) bf16 Bs[TN * BK];  // 8 KB
  const int tid  = threadIdx.x;
  const int wave = tid >> 6;
  const int lane = tid & 63;
  const int zb   = blockIdx.z;
  A = A + (size_t)zb * As_z;
  B = B + (size_t)zb * Bs_z;
  const float* bias = (MODE == 0 && zb) ? bias1 : bias0;

  const int row0 = blockIdx.x * TM;
  const int col0 = blockIdx.y * TN;
  const int wm = (wave & 1) * 64;   // 2x2 waves, each owns 64x64
  const int wn = (wave >> 1) * 64;
  const int lm   = lane & 15;
  const int quad = lane >> 4;

  v4f acc[4][4] = {};

  const char* gA = (const char*)A;
  const char* gB = (const char*)B;
  const size_t sA = (size_t)lda * 2;
  const size_t sB = (size_t)ldb * 2;

  // XOR-swizzled staging: LDS granule (row*4 + qs) holds global 16B chunk
  // (row, q = qs ^ ((row>>1)&3)).  Lane layout of global_load_lds is fixed
  // (base + lane*16), so we permute the GLOBAL address instead.
  // R2 measured: SQ_LDS_BANK_CONFLICT 4.19M -> 0.
  const int row_s = tid >> 2;                        // 0..63 (issue 0)
  const int qg    = (tid & 3) ^ ((row_s >> 1) & 3);  // same for issue 1 (+64 rows)
  const int kb    = qg * 16;
  char* ldsA = (char*)As + wave * 1024;  // wave-uniform base; HW adds lane*16
  char* ldsB = (char*)Bs + wave * 1024;

  const int kIters = K / BK;
  for (int kt = 0; kt < kIters; ++kt) {
    const size_t kOff = (size_t)kt * (BK * 2);
    gload_lds16(gA + (size_t)(row0 + row_s) * sA + kOff + kb, ldsA);
    gload_lds16(gA + (size_t)(row0 + row_s + 64) * sA + kOff + kb, ldsA + 4096);
    gload_lds16(gB + (size_t)(col0 + row_s) * sB + kOff + kb, ldsB);
    gload_lds16(gB + (size_t)(col0 + row_s + 64) * sB + kOff + kb, ldsB + 4096);
    __syncthreads();  // drains vmcnt for global_load_lds + barrier

    // read-side swizzle matches the staging permutation
    const int sw8 = ((quad ^ ((lane >> 1) & 3)) * 8);
    v8bf av[4], bv[4];
#pragma unroll
    for (int i = 0; i < 4; ++i)
      av[i] = *(const v8bf*)&As[(wm + i * 16 + lm) * BK + sw8];
#pragma unroll
    for (int j = 0; j < 4; ++j)
      bv[j] = *(const v8bf*)&Bs[(wn + j * 16 + lm) * BK + sw8];
#pragma unroll
    for (int i = 0; i < 4; ++i)
#pragma unroll
      for (int j = 0; j < 4; ++j)
        acc[i][j] = __builtin_amdgcn_mfma_f32_16x16x32_bf16(av[i], bv[j], acc[i][j], 0, 0, 0);
    __syncthreads();
  }

  // epilogue: C/D layout col=lane&15, row=quad*4+reg  [m89-verified]
#pragma unroll
  for (int i = 0; i < 4; ++i) {
    const int grow0 = row0 + wm + i * 16 + quad * 4;
#pragma unroll
    for (int j = 0; j < 4; ++j) {
      const int gcol = col0 + wn + j * 16 + lm;
      float badd = 0.f;
      if (MODE == 0 || MODE == 1) badd = bias[gcol];
      if (MODE == 1) {
        // batch-transposed vpT store, 4 consecutive s -> one 8B store
        const int b = grow0 >> 12, s = grow0 & 4095;
        v4bf o;
#pragma unroll
        for (int r = 0; r < 4; ++r) o[r] = (bf16)(acc[i][j][r] + badd);
        *(v4bf*)&((bf16*)Cv)[((size_t)(b * DIMV + gcol)) * SEQ + s] = o;
      } else {
#pragma unroll
        for (int r = 0; r < 4; ++r) {
          const int grow = grow0 + r;
          float v = acc[i][j][r];
          if (MODE == 0) {
            ((bf16*)Cv)[(size_t)zb * Cs_z + (size_t)grow * ldc + gcol] = (bf16)(v + badd);
          } else if (MODE == 2) {
            v = 1.f / (1.f + __expf(v * -0.0625f));  // sigmoid(v/16)
            ((bf16*)Cv)[(size_t)zb * Cs_z + (size_t)grow * ldc + gcol] = (bf16)v;
          } else {  // MODE 3
            ((float*)Cv)[(size_t)zb * Cs_z + (size_t)grow * ldc + gcol] = v;
          }
        }
      }
    }
  }
}

extern "C" void kernel_launch(void* const* d_in, const int* in_sizes, int n_in,
                              void* d_out, int out_size, void* d_ws, size_t ws_size,
                              hipStream_t stream) {
  const float* q  = (const float*)d_in[0];
  const float* k  = (const float*)d_in[1];
  const float* v  = (const float*)d_in[2];
  const float* Wq = (const float*)d_in[3];
  const float* bq = (const float*)d_in[4];
  const float* Wk = (const float*)d_in[5];
  const float* bk = (const float*)d_in[6];
  const float* Wv = (const float*)d_in[7];
  const float* bv = (const float*)d_in[8];
  float* out = (float*)d_out;

  const size_t MB = 1024 * 1024;
  char* ws = (char*)d_ws;

  // Batch-group size g chosen by available ws (deterministic each call):
  //   g=4: z-region 128 MB, total 179 MiB
  //   g=2: z-region  64 MB, total 115 MiB
  //   g=1: R2 layout, 83 MiB (k16 overlays vpT)
  int g;
  size_t zcap;
  if (ws_size >= 188 * MB)      { g = 4; zcap = 128 * MB; }
  else if (ws_size >= 121 * MB) { g = 2; zcap = 64 * MB; }
  else                          { g = 1; zcap = 64 * MB; /* special overlay */ }

  bf16 *castA, *castB, *zbuf, *Wq16, *Wk16, *Wv16, *qp16, *kp16, *vpT;
  if (g >= 2) {
    castA = (bf16*)ws;               // 32 MB
    castB = (bf16*)(ws + 32 * MB);   // 32 MB
    zbuf  = (bf16*)ws;               // g*32 MB (casts dead by then)
    char* p = ws + zcap;
    Wq16 = (bf16*)p;             p += 524288;
    Wk16 = (bf16*)p;             p += 524288;
    Wv16 = (bf16*)p;             p += 2097152;
    qp16 = (bf16*)p;             p += 8388608;
    kp16 = (bf16*)p;             p += 8388608;
    vpT  = (bf16*)p;
  } else {
    // R1/R2-proven 87 MB layout
    castA = (bf16*)ws;               // 32 MB (also zbuf)
    zbuf  = castA;
    char* p = ws + 32 * MB;
    Wq16 = (bf16*)p;             p += 524288;
    Wk16 = (bf16*)p;             p += 524288;
    Wv16 = (bf16*)p;             p += 2097152;
    qp16 = (bf16*)p;             p += 8388608;
    kp16 = (bf16*)p;             p += 8388608;
    vpT  = (bf16*)p;
    castB = vpT;                     // k16 overlays vpT until kp GEMM done
  }

  const int NQKV = BATCH * SEQ * DIMV;  // 16777216

  auto cast = [&](const float* src, bf16* dst, int n) {
    int n4 = n / 4;
    cast_f32_bf16<<<dim3((n4 + 255) / 256), dim3(256), 0, stream>>>(src, dst, n4);
  };

  cast(Wq, Wq16, QKD * DIMV);
  cast(Wk, Wk16, QKD * DIMV);
  cast(Wv, Wv16, DIMV * DIMV);
  cast(q, castA, NQKV);  // q16
  cast(k, castB, NQKV);  // k16

  // qp/kp dual launch: zb=0 -> qp = q16@Wq16^T+bq; zb=1 -> kp = k16@Wk16^T+bk
  gemm_nt<0><<<dim3(BATCH * SEQ / TM, QKD / TN, 2), dim3(256), 0, stream>>>(
      castA, (long)(castB - castA), Wq16, (long)(QKD * DIMV), bq, bk,
      qp16, (long)(kp16 - qp16), DIMV, DIMV, DIMV, QKD);

  // vpT: all batches, flat M=16384, batch-decomposed transposed store
  cast(v, castA, NQKV);  // v16 (q16 dead)
  gemm_nt<1><<<dim3(BATCH * SEQ / TM, DIMV / TN, 1), dim3(256), 0, stream>>>(
      castA, 0L, Wv16, 0L, bv, nullptr,
      vpT, 0L, DIMV, DIMV, DIMV, 0);   // overwrites k16 if g==1 (kp done)

  // per group: z = sigmoid(qp@kp^T/16) for g batches; out = z @ vp, full K
  const long zstride = (long)SEQ * SEQ;
  for (int ig = 0; ig < BATCH / g; ++ig) {
    const size_t b0 = (size_t)ig * g;
    gemm_nt<2><<<dim3(SEQ / TM, SEQ / TN, g), dim3(256), 0, stream>>>(
        qp16 + b0 * SEQ * QKD, (long)(SEQ * QKD),
        kp16 + b0 * SEQ * QKD, (long)(SEQ * QKD),
        nullptr, nullptr, zbuf, zstride, QKD, QKD, QKD, SEQ);
    gemm_nt<3><<<dim3(SEQ / TM, DIMV / TN, g), dim3(256), 0, stream>>>(
        zbuf, zstride, vpT + b0 * DIMV * SEQ, (long)(DIMV * SEQ),
        nullptr, nullptr, out + b0 * SEQ * DIMV, (long)(SEQ * DIMV),
        SEQ, SEQ, SEQ, DIMV);
  }
}

// Round 4
// 549.530 us; speedup vs baseline: 1.5212x; 1.0871x over previous
//
#include <hip/hip_runtime.h>
#include <cstdint>
#include <cstddef>

// ScaledDotProduct: qp=q@Wq^T+bq; kp=k@Wk^T+bk; vp=v@Wv^T+bv;
// z=sigmoid(qp@kp^T/16); out=z@vp.  All GEMMs bf16 MFMA (fp32 accum).
// R4: 32x32x16 MFMA (8 MFMA/iter vs 16, higher per-SIMD rate) + pointer-
//     increment staging addresses.  Keeps R2 XOR swizzle (conflicts==0) and
//     R3 batch-grouped single dispatches.

typedef __bf16 bf16;
typedef __bf16 v8bf __attribute__((ext_vector_type(8)));
typedef __bf16 v4bf __attribute__((ext_vector_type(4)));
typedef float  v16f __attribute__((ext_vector_type(16)));

#define DIMV  1024
#define QKD   256
#define BATCH 4
#define SEQ   4096

#define TM 128
#define TN 128
#define BK 32

// ---------------- fp32 -> bf16 cast, 4 elems/thread ----------------
__global__ __launch_bounds__(256) void cast_f32_bf16(const float* __restrict__ in,
                                                     bf16* __restrict__ out, int n4) {
  int i = blockIdx.x * 256 + threadIdx.x;
  if (i >= n4) return;
  const float4 v = reinterpret_cast<const float4*>(in)[i];
  v4bf o;
  o[0] = (bf16)v.x; o[1] = (bf16)v.y; o[2] = (bf16)v.z; o[3] = (bf16)v.w;
  reinterpret_cast<v4bf*>(out)[i] = o;
}

__device__ __forceinline__ void gload_lds16(const void* g, void* l) {
  __builtin_amdgcn_global_load_lds((const __attribute__((address_space(1))) void*)g,
                                   (__attribute__((address_space(3))) void*)l,
                                   16, 0, 0);
}

// NT GEMM: C[m,n] = sum_k A[m,k]*B[n,k]  (A: MxK rows lda, B: NxK rows ldb)
// blockIdx.z offsets A/B/C by As_z/Bs_z/Cs_z ELEMENTS (batch / dual-launch).
// MODE 0: bf16 out = acc + bias[n], row-major (ldc); bias = zb?bias1:bias0
// MODE 1: bf16 out = acc + bias0[n], batch-transposed store:
//         b=grow>>12, s=grow&4095 -> C[((b*DIMV+gcol)*SEQ + s)]
// MODE 2: bf16 out = sigmoid(acc/16), row-major
// MODE 3: f32 out = acc, row-major
template <int MODE>
__global__ __launch_bounds__(256) void gemm_nt(
    const bf16* __restrict__ A, long As_z,
    const bf16* __restrict__ B, long Bs_z,
    const float* __restrict__ bias0, const float* __restrict__ bias1,
    void* __restrict__ Cv, long Cs_z,
    int K, int lda, int ldb, int ldc) {
  __shared__ __align__(16) bf16 As[TM * BK];  // 8 KB
  __shared__ __align__(16) bf16 Bs[TN * BK];  // 8 KB
  const int tid  = threadIdx.x;
  const int wave = tid >> 6;
  const int lane = tid & 63;
  const int zb   = blockIdx.z;
  A = A + (size_t)zb * As_z;
  B = B + (size_t)zb * Bs_z;
  const float* bias = (MODE == 0 && zb) ? bias1 : bias0;

  const int row0 = blockIdx.x * TM;
  const int col0 = blockIdx.y * TN;
  const int wm = (wave & 1) * 64;   // 2x2 waves, each owns 64x64
  const int wn = (wave >> 1) * 64;
  const int l31  = lane & 31;
  const int half = lane >> 5;

  v16f acc[2][2] = {};  // 2x2 of 32x32 tiles per wave

  const char* gA = (const char*)A;
  const char* gB = (const char*)B;
  const size_t sA = (size_t)lda * 2;
  const size_t sB = (size_t)ldb * 2;

  // XOR-swizzled staging: LDS granule (row*4 + qs) holds global 16B chunk
  // (row, q = qs ^ ((row>>1)&3)).  global_load_lds lane layout is fixed
  // (base + lane*16) so we permute the GLOBAL address. [R2: conflicts 4.19M->0]
  const int row_s = tid >> 2;                        // 0..63 (issue 0)
  const int qg    = (tid & 3) ^ ((row_s >> 1) & 3);  // same for issue 1 (+64 rows)
  const int kb    = qg * 16;
  char* ldsA = (char*)As + wave * 1024;  // wave-uniform base; HW adds lane*16
  char* ldsB = (char*)Bs + wave * 1024;

  // strength-reduced global pointers (advance 64 B per K-iter)
  const char* pa0 = gA + (size_t)(row0 + row_s) * sA + kb;
  const char* pa1 = gA + (size_t)(row0 + row_s + 64) * sA + kb;
  const char* pb0 = gB + (size_t)(col0 + row_s) * sB + kb;
  const char* pb1 = gB + (size_t)(col0 + row_s + 64) * sB + kb;

  // LDS read offsets (loop-invariant).  Logical frag for 32x32x16 MFMA:
  // lane reads row (tilerow + l31), k = kk*16 + half*8 .. +8 (16B).
  // Physical granule: q' = q ^ ((row>>1)&3); rows are 32-aligned so
  // (row>>1)&3 == (lane>>1)&3.  off1 = off0 ^ 16 (elems).
  const int swz  = (lane >> 1) & 3;
  const int off0 = (half ^ swz) * 8;         // kk=0, elems within row
  const int off1 = off0 ^ 16;                // kk=1
  const int raA0 = (wm + l31) * BK,      raA1 = (wm + 32 + l31) * BK;
  const int raB0 = (wn + l31) * BK,      raB1 = (wn + 32 + l31) * BK;

  const int kIters = K / BK;
  for (int kt = 0; kt < kIters; ++kt) {
    gload_lds16(pa0, ldsA);
    gload_lds16(pa1, ldsA + 4096);
    gload_lds16(pb0, ldsB);
    gload_lds16(pb1, ldsB + 4096);
    pa0 += BK * 2; pa1 += BK * 2; pb0 += BK * 2; pb1 += BK * 2;
    __syncthreads();  // drains vmcnt for global_load_lds + barrier

    v8bf a[2][2], b[2][2];
    a[0][0] = *(const v8bf*)&As[raA0 + off0];
    a[0][1] = *(const v8bf*)&As[raA0 + off1];
    a[1][0] = *(const v8bf*)&As[raA1 + off0];
    a[1][1] = *(const v8bf*)&As[raA1 + off1];
    b[0][0] = *(const v8bf*)&Bs[raB0 + off0];
    b[0][1] = *(const v8bf*)&Bs[raB0 + off1];
    b[1][0] = *(const v8bf*)&Bs[raB1 + off0];
    b[1][1] = *(const v8bf*)&Bs[raB1 + off1];
#pragma unroll
    for (int kk = 0; kk < 2; ++kk)
#pragma unroll
      for (int i = 0; i < 2; ++i)
#pragma unroll
        for (int j = 0; j < 2; ++j)
          acc[i][j] = __builtin_amdgcn_mfma_f32_32x32x16_bf16(a[i][kk], b[j][kk], acc[i][j], 0, 0, 0);
    __syncthreads();
  }

  // epilogue: 32x32 C/D layout col=lane&31, row=(reg&3)+8*(reg>>2)+4*(lane>>5)
  // [m74/m101-verified]
#pragma unroll
  for (int i = 0; i < 2; ++i) {
    const int rb = row0 + wm + i * 32 + 4 * half;  // + rr + 8*blk
#pragma unroll
    for (int j = 0; j < 2; ++j) {
      const int gcol = col0 + wn + j * 32 + l31;
      float badd = 0.f;
      if (MODE == 0 || MODE == 1) badd = bias[gcol];
      if (MODE == 1) {
        // batch-transposed vpT store; 4 consecutive s -> one 8B store
        const int b = rb >> 12;
        bf16* cb = &((bf16*)Cv)[((size_t)(b * DIMV + gcol)) * SEQ];
        const int s0 = rb & 4095;
#pragma unroll
        for (int blk = 0; blk < 4; ++blk) {
          v4bf o;
#pragma unroll
          for (int rr = 0; rr < 4; ++rr) o[rr] = (bf16)(acc[i][j][4 * blk + rr] + badd);
          *(v4bf*)&cb[s0 + 8 * blk] = o;
        }
      } else {
#pragma unroll
        for (int blk = 0; blk < 4; ++blk)
#pragma unroll
          for (int rr = 0; rr < 4; ++rr) {
            const int grow = rb + 8 * blk + rr;
            float v = acc[i][j][4 * blk + rr];
            if (MODE == 0) {
              ((bf16*)Cv)[(size_t)zb * Cs_z + (size_t)grow * ldc + gcol] = (bf16)(v + badd);
            } else if (MODE == 2) {
              v = 1.f / (1.f + __expf(v * -0.0625f));  // sigmoid(v/16)
              ((bf16*)Cv)[(size_t)zb * Cs_z + (size_t)grow * ldc + gcol] = (bf16)v;
            } else {  // MODE 3
              ((float*)Cv)[(size_t)zb * Cs_z + (size_t)grow * ldc + gcol] = v;
            }
          }
      }
    }
  }
}

extern "C" void kernel_launch(void* const* d_in, const int* in_sizes, int n_in,
                              void* d_out, int out_size, void* d_ws, size_t ws_size,
                              hipStream_t stream) {
  const float* q  = (const float*)d_in[0];
  const float* k  = (const float*)d_in[1];
  const float* v  = (const float*)d_in[2];
  const float* Wq = (const float*)d_in[3];
  const float* bq = (const float*)d_in[4];
  const float* Wk = (const float*)d_in[5];
  const float* bk = (const float*)d_in[6];
  const float* Wv = (const float*)d_in[7];
  const float* bv = (const float*)d_in[8];
  float* out = (float*)d_out;

  const size_t MB = 1024 * 1024;
  char* ws = (char*)d_ws;

  // Batch-group size g chosen by available ws (deterministic each call):
  //   g=4: z-region 128 MB, total 179 MiB
  //   g=2: z-region  64 MB, total 115 MiB
  //   g=1: 87 MiB layout (k16 overlays vpT)
  int g;
  size_t zcap;
  if (ws_size >= 188 * MB)      { g = 4; zcap = 128 * MB; }
  else if (ws_size >= 121 * MB) { g = 2; zcap = 64 * MB; }
  else                          { g = 1; zcap = 64 * MB; }

  bf16 *castA, *castB, *zbuf, *Wq16, *Wk16, *Wv16, *qp16, *kp16, *vpT;
  if (g >= 2) {
    castA = (bf16*)ws;               // 32 MB
    castB = (bf16*)(ws + 32 * MB);   // 32 MB
    zbuf  = (bf16*)ws;               // g*32 MB (casts dead by then)
    char* p = ws + zcap;
    Wq16 = (bf16*)p;             p += 524288;
    Wk16 = (bf16*)p;             p += 524288;
    Wv16 = (bf16*)p;             p += 2097152;
    qp16 = (bf16*)p;             p += 8388608;
    kp16 = (bf16*)p;             p += 8388608;
    vpT  = (bf16*)p;
  } else {
    castA = (bf16*)ws;               // 32 MB (also zbuf)
    zbuf  = castA;
    char* p = ws + 32 * MB;
    Wq16 = (bf16*)p;             p += 524288;
    Wk16 = (bf16*)p;             p += 524288;
    Wv16 = (bf16*)p;             p += 2097152;
    qp16 = (bf16*)p;             p += 8388608;
    kp16 = (bf16*)p;             p += 8388608;
    vpT  = (bf16*)p;
    castB = vpT;                     // k16 overlays vpT until kp GEMM done
  }

  const int NQKV = BATCH * SEQ * DIMV;  // 16777216

  auto cast = [&](const float* src, bf16* dst, int n) {
    int n4 = n / 4;
    cast_f32_bf16<<<dim3((n4 + 255) / 256), dim3(256), 0, stream>>>(src, dst, n4);
  };

  cast(Wq, Wq16, QKD * DIMV);
  cast(Wk, Wk16, QKD * DIMV);
  cast(Wv, Wv16, DIMV * DIMV);
  cast(q, castA, NQKV);  // q16
  cast(k, castB, NQKV);  // k16

  // qp/kp dual launch: zb=0 -> qp = q16@Wq16^T+bq; zb=1 -> kp = k16@Wk16^T+bk
  gemm_nt<0><<<dim3(BATCH * SEQ / TM, QKD / TN, 2), dim3(256), 0, stream>>>(
      castA, (long)(castB - castA), Wq16, (long)(QKD * DIMV), bq, bk,
      qp16, (long)(kp16 - qp16), DIMV, DIMV, DIMV, QKD);

  // vpT: all batches, flat M=16384, batch-decomposed transposed store
  cast(v, castA, NQKV);  // v16 (q16 dead)
  gemm_nt<1><<<dim3(BATCH * SEQ / TM, DIMV / TN, 1), dim3(256), 0, stream>>>(
      castA, 0L, Wv16, 0L, bv, nullptr,
      vpT, 0L, DIMV, DIMV, DIMV, 0);   // overwrites k16 if g==1 (kp done)

  // per group: z = sigmoid(qp@kp^T/16) for g batches; out = z @ vp, full K
  const long zstride = (long)SEQ * SEQ;
  for (int ig = 0; ig < BATCH / g; ++ig) {
    const size_t b0 = (size_t)ig * g;
    gemm_nt<2><<<dim3(SEQ / TM, SEQ / TN, g), dim3(256), 0, stream>>>(
        qp16 + b0 * SEQ * QKD, (long)(SEQ * QKD),
        kp16 + b0 * SEQ * QKD, (long)(SEQ * QKD),
        nullptr, nullptr, zbuf, zstride, QKD, QKD, QKD, SEQ);
    gemm_nt<3><<<dim3(SEQ / TM, DIMV / TN, g), dim3(256), 0, stream>>>(
        zbuf, zstride, vpT + b0 * DIMV * SEQ, (long)(DIMV * SEQ),
        nullptr, nullptr, out + b0 * SEQ * DIMV, (long)(SEQ * DIMV),
        SEQ, SEQ, SEQ, DIMV);
  }
}